// Round 1
// baseline (325.991 us; speedup 1.0000x reference)
//
#include <hip/hip_runtime.h>

#define NR 512
#define NZ 512

__device__ __forceinline__ float interp1(float r, float z, const float* __restrict__ tt) {
    // H=1, RGRID0=ZGRID0=0 -> indices are just clipped floors, inv == 1
    float fr = floorf(r);
    float fz = floorf(z);
    int ir0 = (int)fr;
    int iz0 = (int)fz;
    ir0 = min(max(ir0, 0), NR - 2);
    iz0 = min(max(iz0, 0), NZ - 2);
    float x1 = (float)ir0;
    float y1 = (float)iz0;
    float dx = r - x1;        // (r - x1)
    float wx = 1.0f - dx;     // (x2 - r) since x2 = x1 + 1
    float dz = z - y1;        // (z - y1)
    float wz = 1.0f - dz;     // (y2 - z)
    int base = ir0 * NZ + iz0;
    float Q11 = tt[base];
    float Q12 = tt[base + 1];        // (ir0, iz1)
    float Q21 = tt[base + NZ];       // (ir1, iz0)
    float Q22 = tt[base + NZ + 1];   // (ir1, iz1)
    return Q11 * wx * wz + Q21 * dx * wz + Q12 * wx * dz + Q22 * dx * dz;
}

__global__ void __launch_bounds__(256) interp_kernel(
    const float* __restrict__ r, const float* __restrict__ z,
    const float* __restrict__ tt, float* __restrict__ out, int n4, int n) {
    int i = blockIdx.x * blockDim.x + threadIdx.x;
    if (i < n4) {
        float4 rv = reinterpret_cast<const float4*>(r)[i];
        float4 zv = reinterpret_cast<const float4*>(z)[i];
        float4 o;
        o.x = interp1(rv.x, zv.x, tt);
        o.y = interp1(rv.y, zv.y, tt);
        o.z = interp1(rv.z, zv.z, tt);
        o.w = interp1(rv.w, zv.w, tt);
        reinterpret_cast<float4*>(out)[i] = o;
    } else {
        // scalar tail (n not divisible by 4) — handled by the last thread range
        for (int j = n4 * 4 + (i - n4); j < n; j += 1) {
            // only thread i == n4 handles the tail (at most 3 elements)
            if (i == n4) out[j] = interp1(r[j], z[j], tt);
            break;
        }
    }
}

__global__ void tail_kernel(const float* __restrict__ r, const float* __restrict__ z,
                            const float* __restrict__ tt, float* __restrict__ out,
                            int start, int n) {
    int j = start + blockIdx.x * blockDim.x + threadIdx.x;
    if (j < n) out[j] = interp1(r[j], z[j], tt);
}

extern "C" void kernel_launch(void* const* d_in, const int* in_sizes, int n_in,
                              void* d_out, int out_size, void* d_ws, size_t ws_size,
                              hipStream_t stream) {
    const float* r  = (const float*)d_in[0];
    const float* z  = (const float*)d_in[1];
    const float* tt = (const float*)d_in[2];
    float* out = (float*)d_out;
    int n  = in_sizes[0];
    int n4 = n / 4;

    int block = 256;
    int grid = (n4 + block - 1) / block;
    interp_kernel<<<grid, block, 0, stream>>>(r, z, tt, out, n4, n);

    int tail = n - n4 * 4;
    if (tail > 0) {
        tail_kernel<<<1, 64, 0, stream>>>(r, z, tt, out, n4 * 4, n);
    }
}

// Round 2
// 282.690 us; speedup vs baseline: 1.1532x; 1.1532x over previous
//
#include <hip/hip_runtime.h>

#define NR 512
#define NZ 512

// Packed table: P[ir*NZ+iz] = (tt[ir,iz], tt[ir+1,iz]) for ir in [0,NR-2], iz in [0,NZ-1].
// A single float4 load at P+base gives (Q11, Q21, Q12, Q22).
#define P_ROWS (NR - 1)   // 511
#define P_ELEMS (P_ROWS * NZ)

__global__ void __launch_bounds__(256) build_pack_kernel(
    const float* __restrict__ tt, float2* __restrict__ P) {
    int i = blockIdx.x * blockDim.x + threadIdx.x;  // i = ir*NZ + iz
    if (i < P_ELEMS) {
        float2 v;
        v.x = tt[i];
        v.y = tt[i + NZ];
        P[i] = v;
    }
}

__device__ __forceinline__ float interp_packed(float r, float z,
                                               const float2* __restrict__ P) {
    // H=1, RGRID0=ZGRID0=0 -> indices are clipped floors, inv == 1
    int ir0 = (int)floorf(r);
    int iz0 = (int)floorf(z);
    ir0 = min(max(ir0, 0), NR - 2);
    iz0 = min(max(iz0, 0), NZ - 2);
    float dx = r - (float)ir0;     // (r - x1)
    float wx = 1.0f - dx;          // (x2 - r)
    float dz = z - (float)iz0;     // (z - y1)
    float wz = 1.0f - dz;          // (y2 - z)
    int base = ir0 * NZ + iz0;
    // 16B gather, 8B-aligned (dwordx4 needs only dword alignment on CDNA)
    float4 q = *reinterpret_cast<const float4*>(P + base);
    // q = (Q11, Q21, Q12, Q22)
    return (q.x * wz + q.z * dz) * wx + (q.y * wz + q.w * dz) * dx;
}

__global__ void __launch_bounds__(256) interp_kernel(
    const float* __restrict__ r, const float* __restrict__ z,
    const float2* __restrict__ P, float* __restrict__ out, int n4) {
    int i = blockIdx.x * blockDim.x + threadIdx.x;
    if (i < n4) {
        float4 rv = reinterpret_cast<const float4*>(r)[i];
        float4 zv = reinterpret_cast<const float4*>(z)[i];
        float4 o;
        o.x = interp_packed(rv.x, zv.x, P);
        o.y = interp_packed(rv.y, zv.y, P);
        o.z = interp_packed(rv.z, zv.z, P);
        o.w = interp_packed(rv.w, zv.w, P);
        reinterpret_cast<float4*>(out)[i] = o;
    }
}

__global__ void tail_kernel(const float* __restrict__ r, const float* __restrict__ z,
                            const float2* __restrict__ P, float* __restrict__ out,
                            int start, int n) {
    int j = start + blockIdx.x * blockDim.x + threadIdx.x;
    if (j < n) out[j] = interp_packed(r[j], z[j], P);
}

// Fallback (ws too small): direct 4-scalar-gather version
__device__ __forceinline__ float interp_direct(float r, float z,
                                               const float* __restrict__ tt) {
    int ir0 = (int)floorf(r);
    int iz0 = (int)floorf(z);
    ir0 = min(max(ir0, 0), NR - 2);
    iz0 = min(max(iz0, 0), NZ - 2);
    float dx = r - (float)ir0;
    float wx = 1.0f - dx;
    float dz = z - (float)iz0;
    float wz = 1.0f - dz;
    int base = ir0 * NZ + iz0;
    float Q11 = tt[base], Q12 = tt[base + 1];
    float Q21 = tt[base + NZ], Q22 = tt[base + NZ + 1];
    return (Q11 * wz + Q12 * dz) * wx + (Q21 * wz + Q22 * dz) * dx;
}

__global__ void __launch_bounds__(256) interp_direct_kernel(
    const float* __restrict__ r, const float* __restrict__ z,
    const float* __restrict__ tt, float* __restrict__ out, int n4) {
    int i = blockIdx.x * blockDim.x + threadIdx.x;
    if (i < n4) {
        float4 rv = reinterpret_cast<const float4*>(r)[i];
        float4 zv = reinterpret_cast<const float4*>(z)[i];
        float4 o;
        o.x = interp_direct(rv.x, zv.x, tt);
        o.y = interp_direct(rv.y, zv.y, tt);
        o.z = interp_direct(rv.z, zv.z, tt);
        o.w = interp_direct(rv.w, zv.w, tt);
        reinterpret_cast<float4*>(out)[i] = o;
    }
}

extern "C" void kernel_launch(void* const* d_in, const int* in_sizes, int n_in,
                              void* d_out, int out_size, void* d_ws, size_t ws_size,
                              hipStream_t stream) {
    const float* r  = (const float*)d_in[0];
    const float* z  = (const float*)d_in[1];
    const float* tt = (const float*)d_in[2];
    float* out = (float*)d_out;
    int n  = in_sizes[0];
    int n4 = n / 4;
    int tail = n - n4 * 4;

    int block = 256;
    int grid = (n4 + block - 1) / block;

    size_t need = (size_t)P_ELEMS * sizeof(float2);
    if (ws_size >= need) {
        float2* P = (float2*)d_ws;
        build_pack_kernel<<<(P_ELEMS + block - 1) / block, block, 0, stream>>>(tt, P);
        interp_kernel<<<grid, block, 0, stream>>>(r, z, P, out, n4);
        if (tail > 0)
            tail_kernel<<<1, 64, 0, stream>>>(r, z, P, out, n4 * 4, n);
    } else {
        interp_direct_kernel<<<grid, block, 0, stream>>>(r, z, tt, out, n4);
        // tail: reuse packed tail path is unavailable; handle inline
        if (tail > 0) {
            // small scalar pass over the last <=3 elements via direct kernel on 1 block
            // (indices n4*4..n-1)
            // simple dedicated launch:
            // reuse interp_direct in a tiny kernel
            struct L { };
            // fall through: launch a 1-block kernel
            extern __global__ void tail_direct_kernel(const float*, const float*,
                                                      const float*, float*, int, int);
        }
    }
}